// Round 1
// baseline (207.801 us; speedup 1.0000x reference)
//
#include <hip/hip_runtime.h>
#include <hip/hip_fp16.h>

#define NATOMS 768
#define NM1    767
#define NEDGE  (768*767)       // 589056
#define DIM    64
#define NC     50
#define GAPF   (5.0f/49.0f)
#define NIGAP  (-49.0f/5.0f)
#define G      512
#define STEPF  (5.0f/511.0f)
#define INVSTEP (511.0f/5.0f)
#define LN2F   0.693147180559945f

// ws layout (float offsets)
#define WS_H     0              // 768*64 f32
#define WS_NWA   49152          // 768*64 f16 (24576 float slots)
#define WS_NWB   73728          // 768*64 f16
#define WS_HA    98304          // 768 f32 (+pad)
#define WS_DISTT 99328          // 768*768 f32
#define WS_TT    689152         // 4 tables * 512*64 __half2 = 131072 float slots

__device__ __forceinline__ float softplus05(float x) {
    float bx = 0.5f * x;
    return (bx > 14.0f) ? x : 2.0f * __logf(1.0f + __expf(bx));
}
__device__ __forceinline__ int lane_bcast_i(int v, int l) {
    return __builtin_amdgcn_readlane(v, l);
}
__device__ __forceinline__ float lane_bcast_f(float v, int l) {
    return __uint_as_float((unsigned)__builtin_amdgcn_readlane((int)__float_as_uint(v), l));
}
__device__ __forceinline__ float2 pair2f(unsigned p) {
    __half2 h = *reinterpret_cast<__half2*>(&p);
    return __half22float2(h);
}

// ============ prologue: f16 tables + embed/nw0(f16) + dist transpose ============
__global__ __launch_bounds__(256)
void k_pre(const int* __restrict__ types, const float* __restrict__ dist,
           const float* __restrict__ emb, const float* __restrict__ w1all,
           const float* __restrict__ pw1, const float* __restrict__ pb1,
           const float* __restrict__ pw2, const float* __restrict__ pb2,
           const float* __restrict__ row1, const float* __restrict__ rob1,
           float* __restrict__ ws) {
    __shared__ float s_t[4 * 64];
    const int tid = threadIdx.x, widx = tid >> 6, c = tid & 63;
    float*  h     = ws + WS_H;
    __half* nwh   = (__half*)(ws + WS_NWA);
    float*  distT = ws + WS_DISTT;
    __half* TTh   = (__half*)(ws + WS_TT);
    const int b = blockIdx.x;

    if (b < 512) {
        const int w = b * 4 + widx, tbl = w >> 9, g = w & 511;
        const float d = g * STEPF;
        float val;
        if (tbl < 3) {
            const float* W1 = pw1 + tbl * NC * DIM;
            float t1 = pb1[tbl * DIM + c];
            for (int k = 0; k < NC; ++k) {
                float x = d - GAPF * (float)k;
                t1 = fmaf(__expf(NIGAP * x * x), W1[k * DIM + c], t1);
            }
            s_t[widx * 64 + c] = softplus05(t1);     // wave-local lockstep
            const float* W2 = pw2 + tbl * DIM * DIM;
            val = pb2[tbl * DIM + c];
            #pragma unroll 8
            for (int k = 0; k < DIM; ++k)
                val = fmaf(s_t[widx * 64 + k], W2[k * DIM + c], val);
        } else {
            val = rob1[c];
            for (int k = 0; k < NC; ++k) {
                float x = d - GAPF * (float)k;
                val = fmaf(__expf(NIGAP * x * x), row1[(2 + k) * DIM + c], val);
            }
        }
        // paired f16 layout: entry (g,c) holds (T[g][c], T[g+1][c]) as __half2
        __half* TTt = TTh + tbl * (G * DIM * 2);
        TTt[(g * DIM + c) * 2] = __float2half(val);
        if (g > 0) TTt[((g - 1) * DIM + c) * 2 + 1] = __float2half(val);
    } else if (b < 704) {
        const int i = (b - 512) * 4 + widx;
        float hv = emb[types[i] * DIM + c];
        h[i * DIM + c] = hv;
        s_t[widx * 64 + c] = hv;                     // wave-local
        float acc = 0.0f;
        #pragma unroll 8
        for (int k = 0; k < DIM; ++k)
            acc = fmaf(s_t[widx * 64 + k], w1all[k * DIM + c], acc);
        nwh[i * DIM + c] = __float2half(acc);
    } else {
        const int idx = (b - 704) * 256 + tid;       // < 768*768
        const int j = idx / NATOMS, i = idx - j * NATOMS;
        distT[idx] = (i == j) ? 0.0f : dist[i * NM1 + (j - (j > i))];
    }
}

// ============ conv layer: LDS-resident table, 3 dests per block ============
// 256 blocks x 8 waves; block b owns dests {3b, 3b+1, 3b+2}.
// Wave widx covers sources [widx*96, widx*96+96) for each dest.
// Table reads become ds_read_b32 (2-way bank alias = free) instead of
// random L2 loads.  Tail MLPs for the 3 dests run on waves 0..2 in parallel.
__global__ __launch_bounds__(512)
void k_edgeupd(const unsigned* __restrict__ TTl, const float* __restrict__ distT,
               const __half* __restrict__ nwin,
               const float* __restrict__ qw1, const float* __restrict__ qb1,
               const float* __restrict__ qw2, const float* __restrict__ qb2,
               float* __restrict__ h,
               const float* __restrict__ wnext, __half* __restrict__ nwout,
               const float* __restrict__ auw1, const float* __restrict__ aub1,
               const float* __restrict__ auw2, const float* __restrict__ aub2,
               float* __restrict__ ha, int last) {
    __shared__ unsigned s_tab[G * DIM];     // 128 KB paired f16 table
    __shared__ float s_part[3][8][64];      // 6 KB
    __shared__ float s_upd[3][192];         // 2.25 KB
    const int tid = threadIdx.x, widx = tid >> 6, c = tid & 63;
    const int b = blockIdx.x;
    const int s0 = widx * 96;

    { // ---- stage the whole paired table into LDS (one time per block) ----
        const uint4* src = (const uint4*)TTl;
        uint4* dst = (uint4*)s_tab;
        #pragma unroll
        for (int it = 0; it < 16; ++it)
            dst[tid + it * 512] = src[tid + it * 512];
    }
    __syncthreads();

    for (int dd = 0; dd < 3; ++dd) {
        const int j = b * 3 + dd;
        const float* drow = distT + j * NATOMS;
        float csum = 0.0f;
        { // ---- chunk A: sources s0 .. s0+63, lane c holds (g,f) of s0+c ----
            float d = drow[s0 + c];
            float pos = d * INVSTEP;
            int g = (int)pos;
            g = (g < 0) ? 0 : ((g > 510) ? 510 : g);
            float f = pos - (float)g;
            int kw = g << 6;                         // dword index of row g
            #pragma unroll 8
            for (int it = 0; it < 64; ++it) {
                int kwu = lane_bcast_i(kw, it);
                float fu = lane_bcast_f(f, it);
                float2 tt = pair2f(s_tab[kwu + c]);
                float e = fmaf(fu, tt.y - tt.x, tt.x);
                float nwv = __half2float(nwin[(s0 + it) * DIM + c]);
                csum = fmaf(e, nwv, csum);
            }
        }
        { // ---- chunk B: sources s0+64 .. s0+95 (32), lanes mirrored via c&31 ----
            float d = drow[s0 + 64 + (c & 31)];
            float pos = d * INVSTEP;
            int g = (int)pos;
            g = (g < 0) ? 0 : ((g > 510) ? 510 : g);
            float f = pos - (float)g;
            int kw = g << 6;
            #pragma unroll 8
            for (int it = 0; it < 32; ++it) {
                int kwu = lane_bcast_i(kw, it);
                float fu = lane_bcast_f(f, it);
                float2 tt = pair2f(s_tab[kwu + c]);
                float e = fmaf(fu, tt.y - tt.x, tt.x);
                float nwv = __half2float(nwin[(s0 + 64 + it) * DIM + c]);
                csum = fmaf(e, nwv, csum);
            }
        }
        s_part[dd][widx][c] = csum;
    }
    __syncthreads();

    if (widx < 3) {
        const int dd = widx;
        const int j = b * 3 + dd;
        float tot = 0.0f;
        #pragma unroll
        for (int w8 = 0; w8 < 8; ++w8) tot += s_part[dd][w8][c];
        // remove fake i==j term: distT diag=0 -> g=0,f=0 -> e = T[0][c] exactly
        float2 t0 = pair2f(s_tab[c]);
        tot -= t0.x * __half2float(nwin[j * DIM + c]);
        // node MLP (wave-local LDS, lockstep)
        float* su = s_upd[dd];
        su[c] = tot;
        float t = qb1[c];
        #pragma unroll 8
        for (int k = 0; k < DIM; ++k) t = fmaf(su[k], qw1[k * DIM + c], t);
        su[64 + c] = softplus05(t);
        float o = qb2[c];
        #pragma unroll 8
        for (int k = 0; k < DIM; ++k) o = fmaf(su[64 + k], qw2[k * DIM + c], o);
        float hn = h[j * DIM + c] + o;
        h[j * DIM + c] = hn;
        su[128 + c] = hn;
        if (!last) {
            float v = 0.0f;
            #pragma unroll 8
            for (int k = 0; k < DIM; ++k) v = fmaf(su[128 + k], wnext[k * DIM + c], v);
            nwout[j * DIM + c] = __float2half(v);
        } else {
            float t2 = aub1[c];
            #pragma unroll 8
            for (int k = 0; k < DIM; ++k) t2 = fmaf(su[128 + k], auw1[k * DIM + c], t2);
            t2 = ((t2 > 20.0f) ? t2 : __logf(1.0f + __expf(t2))) - LN2F;
            float v = t2 * auw2[c];
            #pragma unroll
            for (int s = 32; s > 0; s >>= 1) v += __shfl_down(v, s, 64);
            if (c == 0) ha[j] = v + aub2[0];
        }
    }
}

// ============ readout (proven logic, f16 table) ============
__global__ __launch_bounds__(256)
void k_ro(const float* __restrict__ dist, const int* __restrict__ src,
          const int* __restrict__ dst, const float* __restrict__ ha,
          const __half2* __restrict__ TTro,
          const float* __restrict__ row1, const float* __restrict__ row2,
          const float* __restrict__ rob2, float* __restrict__ out) {
    __shared__ float4 s_pre[4][64];
    __shared__ float s_h[4][16 * 65];
    __shared__ float s_w2[128];
    const int tid = threadIdx.x, widx = tid >> 6, c = tid & 63;
    if (tid < 128) s_w2[tid] = row2[tid];
    __syncthreads();
    const int ebase = (blockIdx.x * 4 + widx) * 64;
    {
        int eg = ebase + c;
        float d = dist[eg];
        float pos = d * INVSTEP;
        int kk = (int)pos;
        kk = (kk < 0) ? 0 : ((kk > 510) ? 510 : kk);
        float fa = ha[src[eg]], fb = ha[dst[eg]];
        s_pre[widx][c] = make_float4(__int_as_float(kk * 256), pos - (float)kk, fa, fb);
    }
    const char* TTb2 = (const char*)TTro + c * 4;
    const float wa = row1[c], wb = row1[DIM + c];
    const int e2 = (c >> 1) & 15, p2 = c & 1, kh = c >> 5;
    const float bias2 = (kh == 0) ? rob2[p2] : 0.0f;
    float* sh = s_h[widx];
    #pragma unroll
    for (int ch = 0; ch < 4; ++ch) {
        #pragma unroll 4
        for (int e = 0; e < 16; ++e) {               // lane = channel
            float4 p = s_pre[widx][ch * 16 + e];
            float2 tt = __half22float2(*(const __half2*)(TTb2 + __float_as_int(p.x)));
            float hv = fmaf(p.y, tt.y - tt.x, tt.x);
            hv = fmaf(p.z, wa, hv);
            hv = fmaf(p.w, wb, hv);
            sh[e * 65 + c] = fmaxf(hv, 0.0f);
        }
        // lane = (khalf, edge, logit); half-k dot then combine
        float lsum = bias2;
        #pragma unroll 8
        for (int k8 = 0; k8 < 32; ++k8) {
            int k = kh * 32 + k8;
            lsum = fmaf(sh[e2 * 65 + k], s_w2[2 * k + p2], lsum);
        }
        lsum += __shfl_xor(lsum, 32, 64);
        float other = __shfl_xor(lsum, 1, 64);
        float m = fmaxf(lsum, other);
        float ea = __expf(lsum - m), eb = __expf(other - m);
        float r = ea / (ea + eb);
        if (c < 32) out[ebase * 2 + ch * 32 + c] = r;
    }
}

extern "C" void kernel_launch(void* const* d_in, const int* in_sizes, int n_in,
                              void* d_out, int out_size, void* d_ws, size_t ws_size,
                              hipStream_t stream) {
    const int*   types = (const int*)d_in[0];
    const float* dist  = (const float*)d_in[1];
    const int*   srcI  = (const int*)d_in[2];
    const int*   dstI  = (const int*)d_in[3];
    const float* emb   = (const float*)d_in[4];
    const float* w1    = (const float*)d_in[5];
    const float* pw1   = (const float*)d_in[6];
    const float* pb1   = (const float*)d_in[7];
    const float* pw2   = (const float*)d_in[8];
    const float* pb2   = (const float*)d_in[9];
    const float* qw1   = (const float*)d_in[10];
    const float* qb1   = (const float*)d_in[11];
    const float* qw2   = (const float*)d_in[12];
    const float* qb2   = (const float*)d_in[13];
    const float* auw1  = (const float*)d_in[14];
    const float* aub1  = (const float*)d_in[15];
    const float* auw2  = (const float*)d_in[16];
    const float* aub2  = (const float*)d_in[17];
    const float* row1  = (const float*)d_in[18];
    const float* rob1  = (const float*)d_in[19];
    const float* row2  = (const float*)d_in[20];
    const float* rob2  = (const float*)d_in[21];

    float* ws   = (float*)d_ws;
    float* outp = (float*)d_out;
    const unsigned* TT = (const unsigned*)(ws + WS_TT);
    __half* nwbuf[2] = { (__half*)(ws + WS_NWA), (__half*)(ws + WS_NWB) };

    k_pre<<<3008, 256, 0, stream>>>(types, dist, emb, w1, pw1, pb1, pw2, pb2,
                                    row1, rob1, ws);
    for (int l = 0; l < 3; ++l) {
        k_edgeupd<<<256, 512, 0, stream>>>(TT + l * (G * DIM),
            ws + WS_DISTT, nwbuf[l & 1],
            qw1 + l * DIM * DIM, qb1 + l * DIM,
            qw2 + l * DIM * DIM, qb2 + l * DIM,
            ws + WS_H,
            (l < 2) ? (w1 + (l + 1) * DIM * DIM) : w1, nwbuf[(l + 1) & 1],
            auw1, aub1, auw2, aub2, ws + WS_HA, (l == 2) ? 1 : 0);
    }
    k_ro<<<2301, 256, 0, stream>>>(dist, srcI, dstI, ws + WS_HA,
                                   (const __half2*)(TT + 3 * (G * DIM)),
                                   row1, row2, rob2, outp);
}

// Round 2
// 190.656 us; speedup vs baseline: 1.0899x; 1.0899x over previous
//
#include <hip/hip_runtime.h>
#include <hip/hip_fp16.h>

#define NATOMS 768
#define NM1    767
#define NEDGE  (768*767)       // 589056
#define DIM    64
#define NC     50
#define GAPF   (5.0f/49.0f)
#define NIGAP  (-49.0f/5.0f)
#define G      512
#define STEPF  (5.0f/511.0f)
#define INVSTEP (511.0f/5.0f)
#define LN2F   0.693147180559945f

// ws layout (float offsets)
#define WS_H     0              // 768*64 f32
#define WS_NWA   49152          // 768*64 f16 (24576 float slots)
#define WS_NWB   73728          // 768*64 f16
#define WS_HA    98304          // 768 f32 (+pad)
#define WS_DISTT 99328          // 768*768 f32
#define WS_TT    689152         // 4 tables * 512*64 __half2 = 131072 float slots

__device__ __forceinline__ float softplus05(float x) {
    float bx = 0.5f * x;
    return (bx > 14.0f) ? x : 2.0f * __logf(1.0f + __expf(bx));
}
__device__ __forceinline__ int lane_bcast_i(int v, int l) {
    return __builtin_amdgcn_readlane(v, l);
}
__device__ __forceinline__ float lane_bcast_f(float v, int l) {
    return __uint_as_float((unsigned)__builtin_amdgcn_readlane((int)__float_as_uint(v), l));
}

// ============ prologue: f16 tables + embed/nw0(f16) + dist transpose ============
// grid: [0,512)   table build (4 waves/block, one (tbl,g) per wave)
//       [512,704) embedding + nw0
//       [704,848) 64x64 LDS-tiled coalesced transpose of dist -> distT
__global__ __launch_bounds__(256)
void k_pre(const int* __restrict__ types, const float* __restrict__ dist,
           const float* __restrict__ emb, const float* __restrict__ w1all,
           const float* __restrict__ pw1, const float* __restrict__ pb1,
           const float* __restrict__ pw2, const float* __restrict__ pb2,
           const float* __restrict__ row1, const float* __restrict__ rob1,
           float* __restrict__ ws) {
    __shared__ float s_t[4 * 64];
    __shared__ float s_tile[64][65];
    const int tid = threadIdx.x, widx = tid >> 6, c = tid & 63;
    float*  h     = ws + WS_H;
    __half* nwh   = (__half*)(ws + WS_NWA);
    float*  distT = ws + WS_DISTT;
    __half* TTh   = (__half*)(ws + WS_TT);
    const int b = blockIdx.x;

    if (b < 512) {
        const int w = b * 4 + widx, tbl = w >> 9, g = w & 511;
        const float d = g * STEPF;
        float val;
        if (tbl < 3) {
            const float* W1 = pw1 + tbl * NC * DIM;
            float t1 = pb1[tbl * DIM + c];
            for (int k = 0; k < NC; ++k) {
                float x = d - GAPF * (float)k;
                t1 = fmaf(__expf(NIGAP * x * x), W1[k * DIM + c], t1);
            }
            s_t[widx * 64 + c] = softplus05(t1);     // wave-local lockstep
            const float* W2 = pw2 + tbl * DIM * DIM;
            val = pb2[tbl * DIM + c];
            #pragma unroll 8
            for (int k = 0; k < DIM; ++k)
                val = fmaf(s_t[widx * 64 + k], W2[k * DIM + c], val);
        } else {
            val = rob1[c];
            for (int k = 0; k < NC; ++k) {
                float x = d - GAPF * (float)k;
                val = fmaf(__expf(NIGAP * x * x), row1[(2 + k) * DIM + c], val);
            }
        }
        // paired f16 layout: entry (g,c) holds (T[g][c], T[g+1][c]) as __half2
        __half* TTt = TTh + tbl * (G * DIM * 2);
        TTt[(g * DIM + c) * 2] = __float2half(val);
        if (g > 0) TTt[((g - 1) * DIM + c) * 2 + 1] = __float2half(val);
    } else if (b < 704) {
        const int i = (b - 512) * 4 + widx;
        float hv = emb[types[i] * DIM + c];
        h[i * DIM + c] = hv;
        s_t[widx * 64 + c] = hv;                     // wave-local
        float acc = 0.0f;
        #pragma unroll 8
        for (int k = 0; k < DIM; ++k)
            acc = fmaf(s_t[widx * 64 + k], w1all[k * DIM + c], acc);
        nwh[i * DIM + c] = __float2half(acc);
    } else {
        // ---- coalesced tiled transpose: dist(i-major, edge order) -> distT[j][i]
        const int t = b - 704;                       // 144 tiles = 12 x 12
        const int I0 = (t / 12) * 64, J0 = (t % 12) * 64;
        #pragma unroll 4
        for (int r = 0; r < 16; ++r) {               // read rows of dist, coalesced in j
            const int i = I0 + widx * 16 + r;
            const int j = J0 + c;
            s_tile[widx * 16 + r][c] =
                (i == j) ? 0.0f : dist[i * NM1 + (j - (j > i))];
        }
        __syncthreads();
        #pragma unroll 4
        for (int r = 0; r < 16; ++r) {               // write rows of distT, coalesced in i
            const int j = J0 + widx * 16 + r;
            const int i = I0 + c;
            distT[j * NATOMS + i] = s_tile[c][widx * 16 + r];
        }
    }
}

// ============ conv layer (R0-proven structure): block owns dest j ============
// 768 blocks x 8 waves; wave widx covers sources [widx*96, widx*96+96).
__global__ __launch_bounds__(512)
void k_edgeupd(const __half2* __restrict__ TTl, const float* __restrict__ distT,
               const __half* __restrict__ nwin,
               const float* __restrict__ qw1, const float* __restrict__ qb1,
               const float* __restrict__ qw2, const float* __restrict__ qb2,
               float* __restrict__ h,
               const float* __restrict__ wnext, __half* __restrict__ nwout,
               const float* __restrict__ auw1, const float* __restrict__ aub1,
               const float* __restrict__ auw2, const float* __restrict__ aub2,
               float* __restrict__ ha, int last) {
    __shared__ float s_part[8][64];
    __shared__ float s_upd[192];
    const int tid = threadIdx.x, widx = tid >> 6, c = tid & 63;
    const int j = blockIdx.x;
    const int s0 = widx * 96;

    const char* TTb = (const char*)TTl + c * 4;      // lane's column, 4 B/entry
    float csum = 0.0f;
    { // ---- chunk A: sources s0 .. s0+63, lane c holds (g,f) of s0+c ----
        float d = distT[j * NATOMS + s0 + c];
        float pos = d * INVSTEP;
        int g = (int)pos;
        g = (g < 0) ? 0 : ((g > 510) ? 510 : g);
        float f = pos - (float)g;
        int kx = g * 256;                            // byte offset of f16 row
        #pragma unroll 8
        for (int it = 0; it < 64; ++it) {
            int kxu = lane_bcast_i(kx, it);
            float fu = lane_bcast_f(f, it);
            float2 tt = __half22float2(*(const __half2*)(TTb + kxu));
            float e = fmaf(fu, tt.y - tt.x, tt.x);
            float nwv = __half2float(nwin[(s0 + it) * DIM + c]);
            csum = fmaf(e, nwv, csum);
        }
    }
    { // ---- chunk B: sources s0+64 .. s0+95 (32), lanes mirrored via c&31 ----
        float d = distT[j * NATOMS + s0 + 64 + (c & 31)];
        float pos = d * INVSTEP;
        int g = (int)pos;
        g = (g < 0) ? 0 : ((g > 510) ? 510 : g);
        float f = pos - (float)g;
        int kx = g * 256;
        #pragma unroll 8
        for (int it = 0; it < 32; ++it) {
            int kxu = lane_bcast_i(kx, it);
            float fu = lane_bcast_f(f, it);
            float2 tt = __half22float2(*(const __half2*)(TTb + kxu));
            float e = fmaf(fu, tt.y - tt.x, tt.x);
            float nwv = __half2float(nwin[(s0 + 64 + it) * DIM + c]);
            csum = fmaf(e, nwv, csum);
        }
    }
    s_part[widx][c] = csum;
    __syncthreads();

    if (widx == 0) {
        float tot = 0.0f;
        #pragma unroll
        for (int w8 = 0; w8 < 8; ++w8) tot += s_part[w8][c];
        // remove fake i==j term: distT diag=0 -> g=0,f=0 -> e = T[0][c] exactly
        float2 t0 = __half22float2(*(const __half2*)TTb);
        tot -= t0.x * __half2float(nwin[j * DIM + c]);
        // node MLP (wave-local LDS, lockstep)
        s_upd[c] = tot;
        float t = qb1[c];
        #pragma unroll 8
        for (int k = 0; k < DIM; ++k) t = fmaf(s_upd[k], qw1[k * DIM + c], t);
        s_upd[64 + c] = softplus05(t);
        float o = qb2[c];
        #pragma unroll 8
        for (int k = 0; k < DIM; ++k) o = fmaf(s_upd[64 + k], qw2[k * DIM + c], o);
        float hn = h[j * DIM + c] + o;
        h[j * DIM + c] = hn;
        s_upd[128 + c] = hn;
        if (!last) {
            float v = 0.0f;
            #pragma unroll 8
            for (int k = 0; k < DIM; ++k) v = fmaf(s_upd[128 + k], wnext[k * DIM + c], v);
            nwout[j * DIM + c] = __float2half(v);
        } else {
            float t2 = aub1[c];
            #pragma unroll 8
            for (int k = 0; k < DIM; ++k) t2 = fmaf(s_upd[128 + k], auw1[k * DIM + c], t2);
            t2 = ((t2 > 20.0f) ? t2 : __logf(1.0f + __expf(t2))) - LN2F;
            float v = t2 * auw2[c];
            #pragma unroll
            for (int s = 32; s > 0; s >>= 1) v += __shfl_down(v, s, 64);
            if (c == 0) ha[j] = v + aub2[0];
        }
    }
}

// ============ readout (proven logic, f16 table) ============
__global__ __launch_bounds__(256)
void k_ro(const float* __restrict__ dist, const int* __restrict__ src,
          const int* __restrict__ dst, const float* __restrict__ ha,
          const __half2* __restrict__ TTro,
          const float* __restrict__ row1, const float* __restrict__ row2,
          const float* __restrict__ rob2, float* __restrict__ out) {
    __shared__ float4 s_pre[4][64];
    __shared__ float s_h[4][16 * 65];
    __shared__ float s_w2[128];
    const int tid = threadIdx.x, widx = tid >> 6, c = tid & 63;
    if (tid < 128) s_w2[tid] = row2[tid];
    __syncthreads();
    const int ebase = (blockIdx.x * 4 + widx) * 64;
    {
        int eg = ebase + c;
        float d = dist[eg];
        float pos = d * INVSTEP;
        int kk = (int)pos;
        kk = (kk < 0) ? 0 : ((kk > 510) ? 510 : kk);
        float fa = ha[src[eg]], fb = ha[dst[eg]];
        s_pre[widx][c] = make_float4(__int_as_float(kk * 256), pos - (float)kk, fa, fb);
    }
    const char* TTb2 = (const char*)TTro + c * 4;
    const float wa = row1[c], wb = row1[DIM + c];
    const int e2 = (c >> 1) & 15, p2 = c & 1, kh = c >> 5;
    const float bias2 = (kh == 0) ? rob2[p2] : 0.0f;
    float* sh = s_h[widx];
    #pragma unroll
    for (int ch = 0; ch < 4; ++ch) {
        #pragma unroll 4
        for (int e = 0; e < 16; ++e) {               // lane = channel
            float4 p = s_pre[widx][ch * 16 + e];
            float2 tt = __half22float2(*(const __half2*)(TTb2 + __float_as_int(p.x)));
            float hv = fmaf(p.y, tt.y - tt.x, tt.x);
            hv = fmaf(p.z, wa, hv);
            hv = fmaf(p.w, wb, hv);
            sh[e * 65 + c] = fmaxf(hv, 0.0f);
        }
        // lane = (khalf, edge, logit); half-k dot then combine
        float lsum = bias2;
        #pragma unroll 8
        for (int k8 = 0; k8 < 32; ++k8) {
            int k = kh * 32 + k8;
            lsum = fmaf(sh[e2 * 65 + k], s_w2[2 * k + p2], lsum);
        }
        lsum += __shfl_xor(lsum, 32, 64);
        float other = __shfl_xor(lsum, 1, 64);
        float m = fmaxf(lsum, other);
        float ea = __expf(lsum - m), eb = __expf(other - m);
        float r = ea / (ea + eb);
        if (c < 32) out[ebase * 2 + ch * 32 + c] = r;
    }
}

extern "C" void kernel_launch(void* const* d_in, const int* in_sizes, int n_in,
                              void* d_out, int out_size, void* d_ws, size_t ws_size,
                              hipStream_t stream) {
    const int*   types = (const int*)d_in[0];
    const float* dist  = (const float*)d_in[1];
    const int*   srcI  = (const int*)d_in[2];
    const int*   dstI  = (const int*)d_in[3];
    const float* emb   = (const float*)d_in[4];
    const float* w1    = (const float*)d_in[5];
    const float* pw1   = (const float*)d_in[6];
    const float* pb1   = (const float*)d_in[7];
    const float* pw2   = (const float*)d_in[8];
    const float* pb2   = (const float*)d_in[9];
    const float* qw1   = (const float*)d_in[10];
    const float* qb1   = (const float*)d_in[11];
    const float* qw2   = (const float*)d_in[12];
    const float* qb2   = (const float*)d_in[13];
    const float* auw1  = (const float*)d_in[14];
    const float* aub1  = (const float*)d_in[15];
    const float* auw2  = (const float*)d_in[16];
    const float* aub2  = (const float*)d_in[17];
    const float* row1  = (const float*)d_in[18];
    const float* rob1  = (const float*)d_in[19];
    const float* row2  = (const float*)d_in[20];
    const float* rob2  = (const float*)d_in[21];

    float* ws   = (float*)d_ws;
    float* outp = (float*)d_out;
    const __half2* TT = (const __half2*)(ws + WS_TT);
    __half* nwbuf[2] = { (__half*)(ws + WS_NWA), (__half*)(ws + WS_NWB) };

    k_pre<<<848, 256, 0, stream>>>(types, dist, emb, w1, pw1, pb1, pw2, pb2,
                                   row1, rob1, ws);
    for (int l = 0; l < 3; ++l) {
        k_edgeupd<<<768, 512, 0, stream>>>(TT + l * (G * DIM),
            ws + WS_DISTT, nwbuf[l & 1],
            qw1 + l * DIM * DIM, qb1 + l * DIM,
            qw2 + l * DIM * DIM, qb2 + l * DIM,
            ws + WS_H,
            (l < 2) ? (w1 + (l + 1) * DIM * DIM) : w1, nwbuf[(l + 1) & 1],
            auw1, aub1, auw2, aub2, ws + WS_HA, (l == 2) ? 1 : 0);
    }
    k_ro<<<2301, 256, 0, stream>>>(dist, srcI, dstI, ws + WS_HA, TT + 3 * (G * DIM),
                                   row1, row2, rob2, outp);
}

// Round 3
// 185.508 us; speedup vs baseline: 1.1202x; 1.0277x over previous
//
#include <hip/hip_runtime.h>
#include <hip/hip_fp16.h>

#define NATOMS 768
#define NM1    767
#define NEDGE  (768*767)       // 589056
#define DIM    64
#define NC     50
#define GAPF   (5.0f/49.0f)
#define NIGAP  (-49.0f/5.0f)
#define G      512
#define STEPF  (5.0f/511.0f)
#define INVSTEP (511.0f/5.0f)
#define LN2F   0.693147180559945f

// ws layout (float offsets)
#define WS_H     0              // 768*64 f32
#define WS_NWA   49152          // 768*64 f16 PAIRED: half2[(i>>1)*64+c] = (nw[2t][c], nw[2t+1][c])
#define WS_NWB   73728          // 768*64 f16 paired
#define WS_HA    98304          // 768 f32 (+pad)
#define WS_DISTT 99328          // 768*768 f32
#define WS_TT    689152         // 4 tables * 512*64 __half2 = 131072 float slots

__device__ __forceinline__ float softplus05(float x) {
    float bx = 0.5f * x;
    return (bx > 14.0f) ? x : 2.0f * __logf(1.0f + __expf(bx));
}
__device__ __forceinline__ int lane_bcast_i(int v, int l) {
    return __builtin_amdgcn_readlane(v, l);
}
__device__ __forceinline__ float lane_bcast_f(float v, int l) {
    return __uint_as_float((unsigned)__builtin_amdgcn_readlane((int)__float_as_uint(v), l));
}

// ============ prologue: f16 tables + embed/nw0(paired f16) + dist transpose ============
// grid: [0,512)   table build (4 waves/block, one (tbl,g) per wave)
//       [512,704) embedding + nw0
//       [704,848) 64x64 LDS-tiled coalesced transpose of dist -> distT
__global__ __launch_bounds__(256)
void k_pre(const int* __restrict__ types, const float* __restrict__ dist,
           const float* __restrict__ emb, const float* __restrict__ w1all,
           const float* __restrict__ pw1, const float* __restrict__ pb1,
           const float* __restrict__ pw2, const float* __restrict__ pb2,
           const float* __restrict__ row1, const float* __restrict__ rob1,
           float* __restrict__ ws) {
    __shared__ float s_t[4 * 64];
    __shared__ float s_tile[64][65];
    const int tid = threadIdx.x, widx = tid >> 6, c = tid & 63;
    float*  h     = ws + WS_H;
    __half* nwh   = (__half*)(ws + WS_NWA);
    float*  distT = ws + WS_DISTT;
    __half* TTh   = (__half*)(ws + WS_TT);
    const int b = blockIdx.x;

    if (b < 512) {
        const int w = b * 4 + widx, tbl = w >> 9, g = w & 511;
        const float d = g * STEPF;
        float val;
        if (tbl < 3) {
            const float* W1 = pw1 + tbl * NC * DIM;
            float t1 = pb1[tbl * DIM + c];
            for (int k = 0; k < NC; ++k) {
                float x = d - GAPF * (float)k;
                t1 = fmaf(__expf(NIGAP * x * x), W1[k * DIM + c], t1);
            }
            s_t[widx * 64 + c] = softplus05(t1);     // wave-local lockstep
            const float* W2 = pw2 + tbl * DIM * DIM;
            val = pb2[tbl * DIM + c];
            #pragma unroll 8
            for (int k = 0; k < DIM; ++k)
                val = fmaf(s_t[widx * 64 + k], W2[k * DIM + c], val);
        } else {
            val = rob1[c];
            for (int k = 0; k < NC; ++k) {
                float x = d - GAPF * (float)k;
                val = fmaf(__expf(NIGAP * x * x), row1[(2 + k) * DIM + c], val);
            }
        }
        // paired f16 layout: entry (g,c) holds (T[g][c], T[g+1][c]) as __half2
        __half* TTt = TTh + tbl * (G * DIM * 2);
        TTt[(g * DIM + c) * 2] = __float2half(val);
        if (g > 0) TTt[((g - 1) * DIM + c) * 2 + 1] = __float2half(val);
    } else if (b < 704) {
        const int i = (b - 512) * 4 + widx;
        float hv = emb[types[i] * DIM + c];
        h[i * DIM + c] = hv;
        s_t[widx * 64 + c] = hv;                     // wave-local
        float acc = 0.0f;
        #pragma unroll 8
        for (int k = 0; k < DIM; ++k)
            acc = fmaf(s_t[widx * 64 + k], w1all[k * DIM + c], acc);
        nwh[(i >> 1) * 128 + c * 2 + (i & 1)] = __float2half(acc);   // paired
    } else {
        // ---- coalesced tiled transpose: dist(i-major, edge order) -> distT[j][i]
        const int t = b - 704;                       // 144 tiles = 12 x 12
        const int I0 = (t / 12) * 64, J0 = (t % 12) * 64;
        #pragma unroll 4
        for (int r = 0; r < 16; ++r) {               // read rows of dist, coalesced in j
            const int i = I0 + widx * 16 + r;
            const int j = J0 + c;
            s_tile[widx * 16 + r][c] =
                (i == j) ? 0.0f : dist[i * NM1 + (j - (j > i))];
        }
        __syncthreads();
        #pragma unroll 4
        for (int r = 0; r < 16; ++r) {               // write rows of distT, coalesced in i
            const int j = J0 + widx * 16 + r;
            const int i = I0 + c;
            distT[j * NATOMS + i] = s_tile[c][widx * 16 + r];
        }
    }
}

// ============ conv layer: block owns dest j; paired nw; deeper load pipeline ====
// 768 blocks x 8 waves; wave widx covers sources [widx*96, widx*96+96).
__global__ __launch_bounds__(512)
void k_edgeupd(const __half2* __restrict__ TTl, const float* __restrict__ distT,
               const __half2* __restrict__ nwin,
               const float* __restrict__ qw1, const float* __restrict__ qb1,
               const float* __restrict__ qw2, const float* __restrict__ qb2,
               float* __restrict__ h,
               const float* __restrict__ wnext, __half* __restrict__ nwout,
               const float* __restrict__ auw1, const float* __restrict__ aub1,
               const float* __restrict__ auw2, const float* __restrict__ aub2,
               float* __restrict__ ha, int last) {
    __shared__ float s_part[8][64];
    __shared__ float s_upd[192];
    const int tid = threadIdx.x, widx = tid >> 6, c = tid & 63;
    const int j = blockIdx.x;
    const int s0 = widx * 96;

    const char* TTb = (const char*)TTl + c * 4;      // lane's column, 4 B/entry
    float csum = 0.0f;
    { // ---- chunk A: sources s0 .. s0+63 in pairs; lane c holds (g,f) of s0+c ----
        float d = distT[j * NATOMS + s0 + c];
        float pos = d * INVSTEP;
        int g = (int)pos;
        g = (g < 0) ? 0 : ((g > 510) ? 510 : g);
        float f = pos - (float)g;
        int kx = g * 256;                            // byte offset of f16 row
        const __half2* nwrow = nwin + (s0 >> 1) * 64 + c;
        #pragma unroll 8
        for (int t = 0; t < 32; ++t) {
            int kx0 = lane_bcast_i(kx, 2 * t);
            int kx1 = lane_bcast_i(kx, 2 * t + 1);
            float f0 = lane_bcast_f(f, 2 * t);
            float f1 = lane_bcast_f(f, 2 * t + 1);
            float2 ta = __half22float2(*(const __half2*)(TTb + kx0));
            float2 tb = __half22float2(*(const __half2*)(TTb + kx1));
            float2 nwf = __half22float2(nwrow[t * 64]);
            float e0 = fmaf(f0, ta.y - ta.x, ta.x);
            float e1 = fmaf(f1, tb.y - tb.x, tb.x);
            csum = fmaf(e0, nwf.x, csum);
            csum = fmaf(e1, nwf.y, csum);
        }
    }
    { // ---- chunk B: sources s0+64 .. s0+95 in pairs; lanes mirrored via c&31 ----
        float d = distT[j * NATOMS + s0 + 64 + (c & 31)];
        float pos = d * INVSTEP;
        int g = (int)pos;
        g = (g < 0) ? 0 : ((g > 510) ? 510 : g);
        float f = pos - (float)g;
        int kx = g * 256;
        const __half2* nwrow = nwin + ((s0 + 64) >> 1) * 64 + c;
        #pragma unroll 8
        for (int t = 0; t < 16; ++t) {
            int kx0 = lane_bcast_i(kx, 2 * t);
            int kx1 = lane_bcast_i(kx, 2 * t + 1);
            float f0 = lane_bcast_f(f, 2 * t);
            float f1 = lane_bcast_f(f, 2 * t + 1);
            float2 ta = __half22float2(*(const __half2*)(TTb + kx0));
            float2 tb = __half22float2(*(const __half2*)(TTb + kx1));
            float2 nwf = __half22float2(nwrow[t * 64]);
            float e0 = fmaf(f0, ta.y - ta.x, ta.x);
            float e1 = fmaf(f1, tb.y - tb.x, tb.x);
            csum = fmaf(e0, nwf.x, csum);
            csum = fmaf(e1, nwf.y, csum);
        }
    }
    s_part[widx][c] = csum;
    __syncthreads();

    if (widx == 0) {
        float tot = 0.0f;
        #pragma unroll
        for (int w8 = 0; w8 < 8; ++w8) tot += s_part[w8][c];
        // remove fake i==j term: distT diag=0 -> g=0,f=0 -> e = T[0][c] exactly
        float2 t0 = __half22float2(*(const __half2*)TTb);
        float nwj = __half2float(((const __half*)nwin)[(j >> 1) * 128 + c * 2 + (j & 1)]);
        tot -= t0.x * nwj;
        // node MLP (wave-local LDS, lockstep)
        s_upd[c] = tot;
        float t = qb1[c];
        #pragma unroll 8
        for (int k = 0; k < DIM; ++k) t = fmaf(s_upd[k], qw1[k * DIM + c], t);
        s_upd[64 + c] = softplus05(t);
        float o = qb2[c];
        #pragma unroll 8
        for (int k = 0; k < DIM; ++k) o = fmaf(s_upd[64 + k], qw2[k * DIM + c], o);
        float hn = h[j * DIM + c] + o;
        h[j * DIM + c] = hn;
        s_upd[128 + c] = hn;
        if (!last) {
            float v = 0.0f;
            #pragma unroll 8
            for (int k = 0; k < DIM; ++k) v = fmaf(s_upd[128 + k], wnext[k * DIM + c], v);
            nwout[(j >> 1) * 128 + c * 2 + (j & 1)] = __float2half(v);   // paired
        } else {
            float t2 = aub1[c];
            #pragma unroll 8
            for (int k = 0; k < DIM; ++k) t2 = fmaf(s_upd[128 + k], auw1[k * DIM + c], t2);
            t2 = ((t2 > 20.0f) ? t2 : __logf(1.0f + __expf(t2))) - LN2F;
            float v = t2 * auw2[c];
            #pragma unroll
            for (int s = 32; s > 0; s >>= 1) v += __shfl_down(v, s, 64);
            if (c == 0) ha[j] = v + aub2[0];
        }
    }
}

// ============ readout: register edge params + readlane broadcast (no s_pre) ====
__global__ __launch_bounds__(256)
void k_ro(const float* __restrict__ dist, const int* __restrict__ src,
          const int* __restrict__ dst, const float* __restrict__ ha,
          const __half2* __restrict__ TTro,
          const float* __restrict__ row1, const float* __restrict__ row2,
          const float* __restrict__ rob2, float* __restrict__ out) {
    __shared__ float s_h[4][16 * 65];
    __shared__ float s_w2[128];
    const int tid = threadIdx.x, widx = tid >> 6, c = tid & 63;
    if (tid < 128) s_w2[tid] = row2[tid];
    __syncthreads();
    const int ebase = (blockIdx.x * 4 + widx) * 64;

    // lane c holds the params of edge ebase+c, in registers
    int kxv; float ff, fa, fb;
    {
        int eg = ebase + c;
        float d = dist[eg];
        float pos = d * INVSTEP;
        int kk = (int)pos;
        kk = (kk < 0) ? 0 : ((kk > 510) ? 510 : kk);
        kxv = kk * 256;
        ff = pos - (float)kk;
        fa = ha[src[eg]];
        fb = ha[dst[eg]];
    }
    const char* TTb2 = (const char*)TTro + c * 4;
    const float wa = row1[c], wb = row1[DIM + c];
    const int e2 = (c >> 1) & 15, p2 = c & 1, kh = c >> 5;
    const float bias2 = (kh == 0) ? rob2[p2] : 0.0f;
    float* sh = s_h[widx];
    #pragma unroll
    for (int ch = 0; ch < 4; ++ch) {
        #pragma unroll 8
        for (int e = 0; e < 16; ++e) {               // lane = channel
            const int le = ch * 16 + e;
            int kxu   = lane_bcast_i(kxv, le);
            float fu  = lane_bcast_f(ff, le);
            float fau = lane_bcast_f(fa, le);
            float fbu = lane_bcast_f(fb, le);
            float2 tt = __half22float2(*(const __half2*)(TTb2 + kxu));
            float hv = fmaf(fu, tt.y - tt.x, tt.x);
            hv = fmaf(fau, wa, hv);
            hv = fmaf(fbu, wb, hv);
            sh[e * 65 + c] = fmaxf(hv, 0.0f);
        }
        // lane = (khalf, edge, logit); half-k dot then combine
        float lsum = bias2;
        #pragma unroll 8
        for (int k8 = 0; k8 < 32; ++k8) {
            int k = kh * 32 + k8;
            lsum = fmaf(sh[e2 * 65 + k], s_w2[2 * k + p2], lsum);
        }
        lsum += __shfl_xor(lsum, 32, 64);
        float other = __shfl_xor(lsum, 1, 64);
        float m = fmaxf(lsum, other);
        float ea = __expf(lsum - m), eb = __expf(other - m);
        float r = ea / (ea + eb);
        if (c < 32) out[ebase * 2 + ch * 32 + c] = r;
    }
}

extern "C" void kernel_launch(void* const* d_in, const int* in_sizes, int n_in,
                              void* d_out, int out_size, void* d_ws, size_t ws_size,
                              hipStream_t stream) {
    const int*   types = (const int*)d_in[0];
    const float* dist  = (const float*)d_in[1];
    const int*   srcI  = (const int*)d_in[2];
    const int*   dstI  = (const int*)d_in[3];
    const float* emb   = (const float*)d_in[4];
    const float* w1    = (const float*)d_in[5];
    const float* pw1   = (const float*)d_in[6];
    const float* pb1   = (const float*)d_in[7];
    const float* pw2   = (const float*)d_in[8];
    const float* pb2   = (const float*)d_in[9];
    const float* qw1   = (const float*)d_in[10];
    const float* qb1   = (const float*)d_in[11];
    const float* qw2   = (const float*)d_in[12];
    const float* qb2   = (const float*)d_in[13];
    const float* auw1  = (const float*)d_in[14];
    const float* aub1  = (const float*)d_in[15];
    const float* auw2  = (const float*)d_in[16];
    const float* aub2  = (const float*)d_in[17];
    const float* row1  = (const float*)d_in[18];
    const float* rob1  = (const float*)d_in[19];
    const float* row2  = (const float*)d_in[20];
    const float* rob2  = (const float*)d_in[21];

    float* ws   = (float*)d_ws;
    float* outp = (float*)d_out;
    const __half2* TT = (const __half2*)(ws + WS_TT);
    __half2* nwbuf[2] = { (__half2*)(ws + WS_NWA), (__half2*)(ws + WS_NWB) };

    k_pre<<<848, 256, 0, stream>>>(types, dist, emb, w1, pw1, pb1, pw2, pb2,
                                   row1, rob1, ws);
    for (int l = 0; l < 3; ++l) {
        k_edgeupd<<<768, 512, 0, stream>>>(TT + l * (G * DIM),
            ws + WS_DISTT, nwbuf[l & 1],
            qw1 + l * DIM * DIM, qb1 + l * DIM,
            qw2 + l * DIM * DIM, qb2 + l * DIM,
            ws + WS_H,
            (l < 2) ? (w1 + (l + 1) * DIM * DIM) : w1, (__half*)nwbuf[(l + 1) & 1],
            auw1, aub1, auw2, aub2, ws + WS_HA, (l == 2) ? 1 : 0);
    }
    k_ro<<<2301, 256, 0, stream>>>(dist, srcI, dstI, ws + WS_HA, TT + 3 * (G * DIM),
                                   row1, row2, rob2, outp);
}